// Round 6
// baseline (4147.069 us; speedup 1.0000x reference)
//
#include <hip/hip_runtime.h>
#include <math.h>

#define T_STEPS 512
#define NF 4
#define HID 32
#define BN_EPS 1e-5f
#define LOG2E 1.44269504088896340736f

typedef float    f32x4 __attribute__((ext_vector_type(4)));
typedef _Float16 f16x2 __attribute__((ext_vector_type(2)));
typedef _Float16 f16x8 __attribute__((ext_vector_type(8)));

struct F8 { f16x2 p[4]; };

__device__ __forceinline__ f16x2 pk16(float x, float y) {
  return __builtin_bit_cast(f16x2, __builtin_amdgcn_cvt_pkrtz(x, y));
}
__device__ __forceinline__ f16x8 mk8(f16x2 a, f16x2 b, f16x2 c, f16x2 d) {
  F8 f; f.p[0] = a; f.p[1] = b; f.p[2] = c; f.p[3] = d;
  return __builtin_bit_cast(f16x8, f);
}
#if __has_builtin(__builtin_amdgcn_exp2f)
__device__ __forceinline__ float ex2(float x) { return __builtin_amdgcn_exp2f(x); }
#else
__device__ __forceinline__ float ex2(float x) { return exp2f(x); }
#endif
__device__ __forceinline__ float fsigmoid(float x) {
  return __builtin_amdgcn_rcpf(1.0f + __expf(-x));   // validated r1..r10
}
__device__ __forceinline__ f32x4 mfma16(f16x8 a, f16x8 b, f32x4 c) {
  return __builtin_amdgcn_mfma_f32_16x16x32_f16(a, b, c, 0, 0, 0);
}

// r14: bisection verdict from r11/r12/r13 (all failed with byte-identical
// absmax): the packed-f16 h-exchange mechanism is guilty; numerics and dl
// restructure exonerated. This kernel routes around it using the exchange
// pattern that PASSED in this session (r9, and r0's baseline addressing,
// measured 0 bank conflicts):
//   - 2 waves per job, GATE-major split: wave0 computes tiles 0-3 (i,f),
//     wave1 tiles 4-7 (g,o), for all 32 hids.
//   - Each wave activates its own 16 gate elems (EXACT r10 formulas).
//   - Exchange ACTIVATED f32x4 tiles via sact[dbuf][wave][tile][q][n],
//     one barrier, double-buffered by t&1.
//   - BOTH waves then run r10's exact c/h loop redundantly and pack Bh
//     LOCALLY -> Bh bit-identical in both waves, no cross-wave h routing.
// Every arithmetic statement is verbatim r10 => absmax must equal r10's
// (1.953e-3). Per-wave trans/step: 32 own-gate + 16 c/h + 2 dl = 50
// (r10: 82), and 1024 waves engage the full chip (r10: 512 on half).
__global__ __launch_bounds__(128, 1) void hedge_kernel(
    const float* __restrict__ x,
    const float* __restrict__ bn_g, const float* __restrict__ bn_b,
    const float* __restrict__ bn_m, const float* __restrict__ bn_v,
    const float* __restrict__ W_ih, const float* __restrict__ b_ih,
    const float* __restrict__ W_hh, const float* __restrict__ b_hh,
    const float* __restrict__ W1,   const float* __restrict__ b1,
    const float* __restrict__ W2,   const float* __restrict__ b2,
    float* __restrict__ out)
{
  // [dbuf][wave][tile][q][n] of f32x4 — whole-f32x4 writes/reads, the
  // phase-balanced b128 pattern measured at 0 conflicts in r0/r9. 16 KB.
  __shared__ f32x4 sact[2][2][4][4][16];

  const int tid  = threadIdx.x;
  const int w    = tid >> 6;           // wave id: gate pair (0: i,f  1: g,o)
  const int lane = tid & 63;
  const int n    = lane & 15;          // batch column
  const int q    = lane >> 4;          // quad
  const int row  = blockIdx.x * 16 + n;

  // ---- fold BatchNorm (z*scale + shift) into weights and bias
  float scale[5], shift[5];
  #pragma unroll
  for (int f = 0; f < 5; ++f) {
    float s = bn_g[f] * rsqrtf(bn_v[f] + BN_EPS);
    scale[f] = s;
    shift[f] = fmaf(-bn_m[f], s, bn_b[f]);
  }

  const f16x2 zz = {(_Float16)0, (_Float16)0};

  // A/B layouts + K-permutation identical to r8..r10 (verified):
  //   A: m=lane&15, k-slot j -> pi(8q+j) = (j<4) ? 4q+j : 16+4q+(j-4)
  //   D: n=lane&15, m=4q+reg
  // Global tile tl covers gate-rows [16tl,16tl+16): i=0,1 f=2,3 g=4,5 o=6,7.
  // This wave owns tl = 4w+ti, ti=0..3.
  f16x8 Ahh[4], Aih[4];
  f32x4 Cb[4], Wd[4];
  #pragma unroll
  for (int ti = 0; ti < 4; ++ti) {
    const int tl = 4 * w + ti;
    const float ke = (tl == 4 || tl == 5) ? -2.0f * LOG2E : -LOG2E;
    const float* Wr = &W_hh[(16 * tl + n) * HID];
    const f32x4 lo = *(const f32x4*)&Wr[4 * q];
    const f32x4 hi = *(const f32x4*)&Wr[16 + 4 * q];
    Ahh[ti] = mk8(pk16(ke * lo.x, ke * lo.y), pk16(ke * lo.z, ke * lo.w),
                  pk16(ke * hi.x, ke * hi.y), pk16(ke * hi.z, ke * hi.w));
    const float* Wi = &W_ih[(16 * tl + n) * 5];
    Aih[ti] = mk8(q == 0 ? pk16(ke * Wi[0] * scale[0], ke * Wi[1] * scale[1]) : zz,
                  q == 0 ? pk16(ke * Wi[2] * scale[2], ke * Wi[3] * scale[3]) : zz,
                  zz, zz);
    #pragma unroll
    for (int r2 = 0; r2 < 4; ++r2) {
      const int rr = 16 * tl + 4 * q + r2;
      float a = b_ih[rr] + b_hh[rr];
      #pragma unroll
      for (int f = 0; f < 5; ++f) a = fmaf(W_ih[rr * 5 + f], shift[f], a);
      Cb[ti][r2] = ke * a;
      Wd[ti][r2] = ke * W_ih[rr * 5 + 4] * scale[4];
    }
  }
  // MLP fragments (unscaled), redundant in both waves (keeps dl local)
  f16x8 Aw1[2];
  f32x4 Cb1[2], W2v[2];
  #pragma unroll
  for (int p = 0; p < 2; ++p) {
    const float* Wr = &W1[(16 * p + n) * HID];
    const f32x4 lo = *(const f32x4*)&Wr[4 * q];
    const f32x4 hi = *(const f32x4*)&Wr[16 + 4 * q];
    Aw1[p] = mk8(pk16(lo.x, lo.y), pk16(lo.z, lo.w),
                 pk16(hi.x, hi.y), pk16(hi.z, hi.w));
    #pragma unroll
    for (int r2 = 0; r2 < 4; ++r2) {
      Cb1[p][r2] = b1[16 * p + 4 * q + r2];
      W2v[p][r2] = W2[16 * p + 4 * q + r2];
    }
  }
  const float b2s = b2[0];

  const float* xrow = x + (size_t)row * (T_STEPS * NF);
  float*       orow = out + (size_t)row * T_STEPS;

  // full lane-local recurrent state (redundant in both waves, as r10):
  // c for hid = 4q+s (s<4) and 16+4q+(s-4) (s>=4)
  float cst[8] = {0, 0, 0, 0, 0, 0, 0, 0};
  f16x8 Bh = mk8(zz, zz, zz, zz);          // h_{-1} = 0
  f32x4 xv = *(const f32x4*)xrow;          // x_0

  #pragma unroll 1
  for (int t = 0; t < T_STEPS; ++t) {
    const int tn = (t + 1 < T_STEPS) ? t + 1 : t;
    const f32x4 xn = *(const f32x4*)(xrow + tn * NF);   // prefetch x_{t+1}

    // ---- own 4 gate tiles + MLP from h_{t-1}, x_t (r10 order)
    const f16x8 Bz = mk8(q == 0 ? pk16(xv.x, xv.y) : zz,
                         q == 0 ? pk16(xv.z, xv.w) : zz, zz, zz);
    f32x4 Dv[4];
    #pragma unroll
    for (int ti = 0; ti < 4; ++ti)
      Dv[ti] = mfma16(Aih[ti], Bz, mfma16(Ahh[ti], Bh, Cb[ti]));
    const f32x4 M0 = mfma16(Aw1[0], Bh, Cb1[0]);
    const f32x4 M1 = mfma16(Aw1[1], Bh, Cb1[1]);

    // ---- d_{t-1} = sigmoid(relu(M)*W2 + b2), EXACT r10 reduce order
    float y = 0.0f;
    #pragma unroll
    for (int r2 = 0; r2 < 4; ++r2) {
      y = fmaf(W2v[0][r2], fmaxf(M0[r2], 0.0f), y);
      y = fmaf(W2v[1][r2], fmaxf(M1[r2], 0.0f), y);
    }
    y += __builtin_bit_cast(float, __builtin_amdgcn_ds_swizzle(
             __builtin_bit_cast(int, y), 0x401F));      // xor-16 (q^1)
    y += __shfl_xor(y, 32);                             // q^2
    float dl = fsigmoid(y + b2s);
    dl = t ? dl : 0.0f;                                 // reference d_{-1} = 0
    if (w == 0 && q == 0 && t) orow[t - 1] = dl;

    // ---- activate OWN tiles, EXACT r10 per-gate formulas
    f32x4 Ao[4];
    #pragma unroll
    for (int ti = 0; ti < 4; ++ti) {
      const int tl = 4 * w + ti;
      const bool isg = (tl == 4 || tl == 5);
      #pragma unroll
      for (int r2 = 0; r2 < 4; ++r2) {
        const float rc = __builtin_amdgcn_rcpf(
            1.0f + ex2(fmaf(Wd[ti][r2], dl, Dv[ti][r2])));
        Ao[ti][r2] = isg ? fmaf(2.0f, rc, -1.0f) : rc;
      }
    }

    // ---- exchange activated tiles (r9/r0-proven pattern, one barrier)
    const int b = t & 1;
    #pragma unroll
    for (int ti = 0; ti < 4; ++ti) sact[b][w][ti][q][n] = Ao[ti];
    __syncthreads();
    f32x4 Ac[8];
    #pragma unroll
    for (int ti = 0; ti < 4; ++ti) Ac[4 * w + ti] = Ao[ti];
    #pragma unroll
    for (int ti = 0; ti < 4; ++ti) Ac[4 * (1 - w) + ti] = sact[b][1 - w][ti][q][n];

    // ---- c/h update, EXACT r10 loop (redundant in both waves)
    float hN[8];
    #pragma unroll
    for (int s = 0; s < 8; ++s) {
      const int odd = s >> 2, r2 = s & 3;
      const float iv = Ac[0 + odd][r2];
      const float fv = Ac[2 + odd][r2];
      const float gv = Ac[4 + odd][r2];
      const float ov = Ac[6 + odd][r2];
      const float cc = fmaf(fv, cst[s], iv * gv);
      cst[s] = cc;
      const float tc = fmaf(2.0f,
          __builtin_amdgcn_rcpf(1.0f + ex2(-2.0f * LOG2E * cc)), -1.0f);
      hN[s] = ov * tc;
    }
    // Bh slot j (j<4): h[4q+j] = hN[j]; (j>=4): h[16+4q+(j-4)] = hN[j]
    Bh = mk8(pk16(hN[0], hN[1]), pk16(hN[2], hN[3]),
             pk16(hN[4], hN[5]), pk16(hN[6], hN[7]));
    xv = xn;
  }

  // ---- epilogue: d_{T-1} from h_{T-1} (exact r10)
  const f32x4 M0 = mfma16(Aw1[0], Bh, Cb1[0]);
  const f32x4 M1 = mfma16(Aw1[1], Bh, Cb1[1]);
  float y = 0.0f;
  #pragma unroll
  for (int r2 = 0; r2 < 4; ++r2) {
    y = fmaf(W2v[0][r2], fmaxf(M0[r2], 0.0f), y);
    y = fmaf(W2v[1][r2], fmaxf(M1[r2], 0.0f), y);
  }
  y += __builtin_bit_cast(float, __builtin_amdgcn_ds_swizzle(
           __builtin_bit_cast(int, y), 0x401F));
  y += __shfl_xor(y, 32);
  const float dl = fsigmoid(y + b2s);
  if (w == 0 && q == 0) orow[T_STEPS - 1] = dl;
}

extern "C" void kernel_launch(void* const* d_in, const int* in_sizes, int n_in,
                              void* d_out, int out_size, void* d_ws, size_t ws_size,
                              hipStream_t stream) {
  const float* x    = (const float*)d_in[0];
  const float* bn_g = (const float*)d_in[1];
  const float* bn_b = (const float*)d_in[2];
  const float* bn_m = (const float*)d_in[3];
  const float* bn_v = (const float*)d_in[4];
  const float* W_ih = (const float*)d_in[5];
  const float* b_ih = (const float*)d_in[6];
  const float* W_hh = (const float*)d_in[7];
  const float* b_hh = (const float*)d_in[8];
  const float* W1   = (const float*)d_in[9];
  const float* b1   = (const float*)d_in[10];
  const float* W2   = (const float*)d_in[11];
  const float* b2   = (const float*)d_in[12];
  float* out = (float*)d_out;

  const int B = in_sizes[0] / (T_STEPS * NF);   // 8192
  const int grid = B / 16;                      // 2-wave block per 16 rows

  hipLaunchKernelGGL(hedge_kernel, dim3(grid), dim3(128), 0, stream,
                     x, bn_g, bn_b, bn_m, bn_v, W_ih, b_ih, W_hh, b_hh,
                     W1, b1, W2, b2, out);
}

// Round 7
// 662.130 us; speedup vs baseline: 6.2632x; 6.2632x over previous
//
#include <hip/hip_runtime.h>
#include <math.h>

#define T_STEPS 512
#define NF 4
#define HID 32
#define BN_EPS 1e-5f
#define LOG2E 1.44269504088896340736f

typedef float    f32x4 __attribute__((ext_vector_type(4)));
typedef _Float16 f16x2 __attribute__((ext_vector_type(2)));
typedef _Float16 f16x8 __attribute__((ext_vector_type(8)));

struct F8 { f16x2 p[4]; };

__device__ __forceinline__ f16x2 pk16(float x, float y) {
  return __builtin_bit_cast(f16x2, __builtin_amdgcn_cvt_pkrtz(x, y));
}
__device__ __forceinline__ f16x8 mk8(f16x2 a, f16x2 b, f16x2 c, f16x2 d) {
  F8 f; f.p[0] = a; f.p[1] = b; f.p[2] = c; f.p[3] = d;
  return __builtin_bit_cast(f16x8, f);
}
#if __has_builtin(__builtin_amdgcn_exp2f)
__device__ __forceinline__ float ex2(float x) { return __builtin_amdgcn_exp2f(x); }
#else
__device__ __forceinline__ float ex2(float x) { return exp2f(x); }
#endif
__device__ __forceinline__ float fsigmoid(float x) {
  return __builtin_amdgcn_rcpf(1.0f + __expf(-x));   // validated r1..r10
}
__device__ __forceinline__ f32x4 mfma16(f16x8 a, f16x8 b, f32x4 c) {
  return __builtin_amdgcn_mfma_f32_16x16x32_f16(a, b, c, 0, 0, 0);
}

// r15 = r14 with the rule-#20 violation fixed. r14 PASSED (absmax 1.953e-3,
// exchange mechanism proven) but ran 4147us: Ac[4*w+ti] runtime-indexed a
// register f32x4 array with the wave id -> compiler allocated Ac/Ao in
// SCRATCH (VALUBusy 48%, MfmaUtil 0.8%, ~19.7k cyc/step = scratch stall
// signature). Fix: both waves read ALL 8 activated tiles from LDS with
// COMPILE-TIME indices (Ac[k] = sact[b][k>>2][k&3][q][n], k unrolled);
// own tiles round-trip LDS (~4 extra ds_read_b128, latency-hidden).
// No other statement changes; exchanged bits identical to r14.
// Structure (r14): 2 waves/job, GATE-major split (wave0: i,f tiles 0-3;
// wave1: g,o tiles 4-7), activate own tiles (exact r10 formulas), exchange
// activated f32x4 tiles via sact (r0/r9-proven conflict-free addressing,
// one barrier, dbuf), both waves run r10's exact c/h loop redundantly and
// pack Bh locally (bit-identical in both waves).
__global__ __launch_bounds__(128, 1) void hedge_kernel(
    const float* __restrict__ x,
    const float* __restrict__ bn_g, const float* __restrict__ bn_b,
    const float* __restrict__ bn_m, const float* __restrict__ bn_v,
    const float* __restrict__ W_ih, const float* __restrict__ b_ih,
    const float* __restrict__ W_hh, const float* __restrict__ b_hh,
    const float* __restrict__ W1,   const float* __restrict__ b1,
    const float* __restrict__ W2,   const float* __restrict__ b2,
    float* __restrict__ out)
{
  // [dbuf][wave][tile][q][n] of f32x4 — whole-f32x4 writes/reads, the
  // phase-balanced b128 pattern measured at 0 conflicts in r0/r9. 16 KB.
  __shared__ f32x4 sact[2][2][4][4][16];

  const int tid  = threadIdx.x;
  const int w    = tid >> 6;           // wave id: gate pair (0: i,f  1: g,o)
  const int lane = tid & 63;
  const int n    = lane & 15;          // batch column
  const int q    = lane >> 4;          // quad
  const int row  = blockIdx.x * 16 + n;

  // ---- fold BatchNorm (z*scale + shift) into weights and bias
  float scale[5], shift[5];
  #pragma unroll
  for (int f = 0; f < 5; ++f) {
    float s = bn_g[f] * rsqrtf(bn_v[f] + BN_EPS);
    scale[f] = s;
    shift[f] = fmaf(-bn_m[f], s, bn_b[f]);
  }

  const f16x2 zz = {(_Float16)0, (_Float16)0};

  // A/B layouts + K-permutation identical to r8..r10 (verified):
  //   A: m=lane&15, k-slot j -> pi(8q+j) = (j<4) ? 4q+j : 16+4q+(j-4)
  //   D: n=lane&15, m=4q+reg
  // Global tile tl covers gate-rows [16tl,16tl+16): i=0,1 f=2,3 g=4,5 o=6,7.
  // This wave owns tl = 4w+ti, ti=0..3.
  f16x8 Ahh[4], Aih[4];
  f32x4 Cb[4], Wd[4];
  #pragma unroll
  for (int ti = 0; ti < 4; ++ti) {
    const int tl = 4 * w + ti;
    const float ke = (tl == 4 || tl == 5) ? -2.0f * LOG2E : -LOG2E;
    const float* Wr = &W_hh[(16 * tl + n) * HID];
    const f32x4 lo = *(const f32x4*)&Wr[4 * q];
    const f32x4 hi = *(const f32x4*)&Wr[16 + 4 * q];
    Ahh[ti] = mk8(pk16(ke * lo.x, ke * lo.y), pk16(ke * lo.z, ke * lo.w),
                  pk16(ke * hi.x, ke * hi.y), pk16(ke * hi.z, ke * hi.w));
    const float* Wi = &W_ih[(16 * tl + n) * 5];
    Aih[ti] = mk8(q == 0 ? pk16(ke * Wi[0] * scale[0], ke * Wi[1] * scale[1]) : zz,
                  q == 0 ? pk16(ke * Wi[2] * scale[2], ke * Wi[3] * scale[3]) : zz,
                  zz, zz);
    #pragma unroll
    for (int r2 = 0; r2 < 4; ++r2) {
      const int rr = 16 * tl + 4 * q + r2;
      float a = b_ih[rr] + b_hh[rr];
      #pragma unroll
      for (int f = 0; f < 5; ++f) a = fmaf(W_ih[rr * 5 + f], shift[f], a);
      Cb[ti][r2] = ke * a;
      Wd[ti][r2] = ke * W_ih[rr * 5 + 4] * scale[4];
    }
  }
  // MLP fragments (unscaled), redundant in both waves (keeps dl local)
  f16x8 Aw1[2];
  f32x4 Cb1[2], W2v[2];
  #pragma unroll
  for (int p = 0; p < 2; ++p) {
    const float* Wr = &W1[(16 * p + n) * HID];
    const f32x4 lo = *(const f32x4*)&Wr[4 * q];
    const f32x4 hi = *(const f32x4*)&Wr[16 + 4 * q];
    Aw1[p] = mk8(pk16(lo.x, lo.y), pk16(lo.z, lo.w),
                 pk16(hi.x, hi.y), pk16(hi.z, hi.w));
    #pragma unroll
    for (int r2 = 0; r2 < 4; ++r2) {
      Cb1[p][r2] = b1[16 * p + 4 * q + r2];
      W2v[p][r2] = W2[16 * p + 4 * q + r2];
    }
  }
  const float b2s = b2[0];

  const float* xrow = x + (size_t)row * (T_STEPS * NF);
  float*       orow = out + (size_t)row * T_STEPS;

  // full lane-local recurrent state (redundant in both waves, as r10):
  // c for hid = 4q+s (s<4) and 16+4q+(s-4) (s>=4)
  float cst[8] = {0, 0, 0, 0, 0, 0, 0, 0};
  f16x8 Bh = mk8(zz, zz, zz, zz);          // h_{-1} = 0
  f32x4 xv = *(const f32x4*)xrow;          // x_0

  #pragma unroll 1
  for (int t = 0; t < T_STEPS; ++t) {
    const int tn = (t + 1 < T_STEPS) ? t + 1 : t;
    const f32x4 xn = *(const f32x4*)(xrow + tn * NF);   // prefetch x_{t+1}

    // ---- own 4 gate tiles + MLP from h_{t-1}, x_t (r10 order)
    const f16x8 Bz = mk8(q == 0 ? pk16(xv.x, xv.y) : zz,
                         q == 0 ? pk16(xv.z, xv.w) : zz, zz, zz);
    f32x4 Dv[4];
    #pragma unroll
    for (int ti = 0; ti < 4; ++ti)
      Dv[ti] = mfma16(Aih[ti], Bz, mfma16(Ahh[ti], Bh, Cb[ti]));
    const f32x4 M0 = mfma16(Aw1[0], Bh, Cb1[0]);
    const f32x4 M1 = mfma16(Aw1[1], Bh, Cb1[1]);

    // ---- d_{t-1} = sigmoid(relu(M)*W2 + b2), EXACT r10 reduce order
    float y = 0.0f;
    #pragma unroll
    for (int r2 = 0; r2 < 4; ++r2) {
      y = fmaf(W2v[0][r2], fmaxf(M0[r2], 0.0f), y);
      y = fmaf(W2v[1][r2], fmaxf(M1[r2], 0.0f), y);
    }
    y += __builtin_bit_cast(float, __builtin_amdgcn_ds_swizzle(
             __builtin_bit_cast(int, y), 0x401F));      // xor-16 (q^1)
    y += __shfl_xor(y, 32);                             // q^2
    float dl = fsigmoid(y + b2s);
    dl = t ? dl : 0.0f;                                 // reference d_{-1} = 0
    if (w == 0 && q == 0 && t) orow[t - 1] = dl;

    // ---- activate OWN tiles, EXACT r10 per-gate formulas (static Ao index)
    f32x4 Ao[4];
    #pragma unroll
    for (int ti = 0; ti < 4; ++ti) {
      const int tl = 4 * w + ti;
      const bool isg = (tl == 4 || tl == 5);
      #pragma unroll
      for (int r2 = 0; r2 < 4; ++r2) {
        const float rc = __builtin_amdgcn_rcpf(
            1.0f + ex2(fmaf(Wd[ti][r2], dl, Dv[ti][r2])));
        Ao[ti][r2] = isg ? fmaf(2.0f, rc, -1.0f) : rc;
      }
    }

    // ---- exchange activated tiles (one barrier); read back ALL 8 tiles
    //      with COMPILE-TIME register indices (rule #20: no runtime w in
    //      register-array subscripts; runtime w in the LDS address is fine)
    const int b = t & 1;
    #pragma unroll
    for (int ti = 0; ti < 4; ++ti) sact[b][w][ti][q][n] = Ao[ti];
    __syncthreads();
    f32x4 Ac[8];
    #pragma unroll
    for (int k = 0; k < 8; ++k) Ac[k] = sact[b][k >> 2][k & 3][q][n];

    // ---- c/h update, EXACT r10 loop (redundant in both waves)
    float hN[8];
    #pragma unroll
    for (int s = 0; s < 8; ++s) {
      const int odd = s >> 2, r2 = s & 3;
      const float iv = Ac[0 + odd][r2];
      const float fv = Ac[2 + odd][r2];
      const float gv = Ac[4 + odd][r2];
      const float ov = Ac[6 + odd][r2];
      const float cc = fmaf(fv, cst[s], iv * gv);
      cst[s] = cc;
      const float tc = fmaf(2.0f,
          __builtin_amdgcn_rcpf(1.0f + ex2(-2.0f * LOG2E * cc)), -1.0f);
      hN[s] = ov * tc;
    }
    // Bh slot j (j<4): h[4q+j] = hN[j]; (j>=4): h[16+4q+(j-4)] = hN[j]
    Bh = mk8(pk16(hN[0], hN[1]), pk16(hN[2], hN[3]),
             pk16(hN[4], hN[5]), pk16(hN[6], hN[7]));
    xv = xn;
  }

  // ---- epilogue: d_{T-1} from h_{T-1} (exact r10)
  const f32x4 M0 = mfma16(Aw1[0], Bh, Cb1[0]);
  const f32x4 M1 = mfma16(Aw1[1], Bh, Cb1[1]);
  float y = 0.0f;
  #pragma unroll
  for (int r2 = 0; r2 < 4; ++r2) {
    y = fmaf(W2v[0][r2], fmaxf(M0[r2], 0.0f), y);
    y = fmaf(W2v[1][r2], fmaxf(M1[r2], 0.0f), y);
  }
  y += __builtin_bit_cast(float, __builtin_amdgcn_ds_swizzle(
           __builtin_bit_cast(int, y), 0x401F));
  y += __shfl_xor(y, 32);
  const float dl = fsigmoid(y + b2s);
  if (w == 0 && q == 0) orow[T_STEPS - 1] = dl;
}

extern "C" void kernel_launch(void* const* d_in, const int* in_sizes, int n_in,
                              void* d_out, int out_size, void* d_ws, size_t ws_size,
                              hipStream_t stream) {
  const float* x    = (const float*)d_in[0];
  const float* bn_g = (const float*)d_in[1];
  const float* bn_b = (const float*)d_in[2];
  const float* bn_m = (const float*)d_in[3];
  const float* bn_v = (const float*)d_in[4];
  const float* W_ih = (const float*)d_in[5];
  const float* b_ih = (const float*)d_in[6];
  const float* W_hh = (const float*)d_in[7];
  const float* b_hh = (const float*)d_in[8];
  const float* W1   = (const float*)d_in[9];
  const float* b1   = (const float*)d_in[10];
  const float* W2   = (const float*)d_in[11];
  const float* b2   = (const float*)d_in[12];
  float* out = (float*)d_out;

  const int B = in_sizes[0] / (T_STEPS * NF);   // 8192
  const int grid = B / 16;                      // 2-wave block per 16 rows

  hipLaunchKernelGGL(hedge_kernel, dim3(grid), dim3(128), 0, stream,
                     x, bn_g, bn_b, bn_m, bn_v, W_ih, b_ih, W_hh, b_hh,
                     W1, b1, W2, b2, out);
}

// Round 8
// 526.112 us; speedup vs baseline: 7.8825x; 1.2585x over previous
//
#include <hip/hip_runtime.h>
#include <math.h>

#define T_STEPS 512
#define NF 4
#define HID 32
#define BN_EPS 1e-5f
#define LOG2E 1.44269504088896340736f

typedef float    f32x4 __attribute__((ext_vector_type(4)));
typedef _Float16 f16x2 __attribute__((ext_vector_type(2)));
typedef _Float16 f16x8 __attribute__((ext_vector_type(8)));

struct F8 { f16x2 p[4]; };

__device__ __forceinline__ f16x2 pk16(float x, float y) {
  return __builtin_bit_cast(f16x2, __builtin_amdgcn_cvt_pkrtz(x, y));
}
__device__ __forceinline__ f16x8 mk8(f16x2 a, f16x2 b, f16x2 c, f16x2 d) {
  F8 f; f.p[0] = a; f.p[1] = b; f.p[2] = c; f.p[3] = d;
  return __builtin_bit_cast(f16x8, f);
}
#if __has_builtin(__builtin_amdgcn_exp2f)
__device__ __forceinline__ float ex2(float x) { return __builtin_amdgcn_exp2f(x); }
#else
__device__ __forceinline__ float ex2(float x) { return exp2f(x); }
#endif
__device__ __forceinline__ float fsigmoid(float x) {
  return __builtin_amdgcn_rcpf(1.0f + __expf(-x));   // validated r1..r10
}
__device__ __forceinline__ f32x4 mfma16(f16x8 a, f16x8 b, f32x4 c) {
  return __builtin_amdgcn_mfma_f32_16x16x32_f16(a, b, c, 0, 0, 0);
}

// r16 = r10 (444us PASS, single wave, zero barriers/LDS) with ONE change:
// shared-denominator activations, 7 trans/hid instead of 10.
// r15 post-mortem killed the wave-split direction structurally: any 2-way
// split duplicates dl/MLP/pack/loop (~300cyc) + exchange ops -> per-job
// issue 2194 > r10's 1521, and barrier/LDS latency is exposed at 1
// wave/SIMD (r15: 1687 stall cyc/step). Jobs = B/16 = 512 = max
// no-exchange waves; r10's regime is structurally optimal. The remaining
// lever is the trans count (82 x 16cyc = 1312 of 1521 issue cyc):
//   c' = c/(1+zf) + (1-zg)/((1+zi)(1+zg))
//      = [c*(1+zi)(1+zg) + (1-zg)(1+zf)] * rcp((1+zf)(1+zi)(1+zg))
//   h  = sigma(o)*tanh(c') = (1-zc) * rcp((1+zo)(1+zc)),  zc = 2^(-2c'*log2e)
// -> 5 ex2 + 2 rcp per hid (was 6 ex2 + 4 rcp... net 10->7).
// Safety: r11(shared-denom) vs r12(r10-numerics) gave BYTE-IDENTICAL absmax
// under the same exchange bug -> the algebra is numerically equivalent at
// observable level. Saturation: clamp gate ex2 args at 40, zc arg at 80:
// products <= 2^120 (rcp normal), limits reproduce exactly (h -> -sigma(o)
// as c -> -inf), no inf*0.
// Everything else verbatim r10 (layouts, dl path, epilogue).
__global__ __launch_bounds__(64, 1) void hedge_kernel(
    const float* __restrict__ x,
    const float* __restrict__ bn_g, const float* __restrict__ bn_b,
    const float* __restrict__ bn_m, const float* __restrict__ bn_v,
    const float* __restrict__ W_ih, const float* __restrict__ b_ih,
    const float* __restrict__ W_hh, const float* __restrict__ b_hh,
    const float* __restrict__ W1,   const float* __restrict__ b1,
    const float* __restrict__ W2,   const float* __restrict__ b2,
    float* __restrict__ out)
{
  const int lane = threadIdx.x & 63;
  const int n    = lane & 15;          // batch column (and A-fragment row m)
  const int q    = lane >> 4;          // quad
  const int row  = blockIdx.x * 16 + n;

  // ---- fold BatchNorm (z*scale + shift) into weights and bias
  float scale[5], shift[5];
  #pragma unroll
  for (int f = 0; f < 5; ++f) {
    float s = bn_g[f] * rsqrtf(bn_v[f] + BN_EPS);
    scale[f] = s;
    shift[f] = fmaf(-bn_m[f], s, bn_b[f]);
  }

  const f16x2 zz = {(_Float16)0, (_Float16)0};

  // A/B layouts + K-permutation identical to r8..r10 (verified):
  //   A: m=lane&15, k-slot j -> pi(8q+j) = (j<4) ? 4q+j : 16+4q+(j-4)
  //   D: n=lane&15, m=4q+reg
  // Tile t covers gate-rows [16t, 16t+16): i=tiles 0,1  f=2,3  g=4,5  o=6,7.
  f16x8 Ahh[8], Aih[8];
  f32x4 Cb[8], Wd[8];
  #pragma unroll
  for (int tl = 0; tl < 8; ++tl) {
    const float ke = (tl == 4 || tl == 5) ? -2.0f * LOG2E : -LOG2E;
    const float* Wr = &W_hh[(16 * tl + n) * HID];
    const f32x4 lo = *(const f32x4*)&Wr[4 * q];
    const f32x4 hi = *(const f32x4*)&Wr[16 + 4 * q];
    Ahh[tl] = mk8(pk16(ke * lo.x, ke * lo.y), pk16(ke * lo.z, ke * lo.w),
                  pk16(ke * hi.x, ke * hi.y), pk16(ke * hi.z, ke * hi.w));
    const float* Wi = &W_ih[(16 * tl + n) * 5];
    Aih[tl] = mk8(q == 0 ? pk16(ke * Wi[0] * scale[0], ke * Wi[1] * scale[1]) : zz,
                  q == 0 ? pk16(ke * Wi[2] * scale[2], ke * Wi[3] * scale[3]) : zz,
                  zz, zz);
    #pragma unroll
    for (int r2 = 0; r2 < 4; ++r2) {
      const int rr = 16 * tl + 4 * q + r2;
      float a = b_ih[rr] + b_hh[rr];
      #pragma unroll
      for (int f = 0; f < 5; ++f) a = fmaf(W_ih[rr * 5 + f], shift[f], a);
      Cb[tl][r2] = ke * a;
      Wd[tl][r2] = ke * W_ih[rr * 5 + 4] * scale[4];
    }
  }
  // MLP fragments (unscaled)
  f16x8 Aw1[2];
  f32x4 Cb1[2], W2v[2];
  #pragma unroll
  for (int p = 0; p < 2; ++p) {
    const float* Wr = &W1[(16 * p + n) * HID];
    const f32x4 lo = *(const f32x4*)&Wr[4 * q];
    const f32x4 hi = *(const f32x4*)&Wr[16 + 4 * q];
    Aw1[p] = mk8(pk16(lo.x, lo.y), pk16(lo.z, lo.w),
                 pk16(hi.x, hi.y), pk16(hi.z, hi.w));
    #pragma unroll
    for (int r2 = 0; r2 < 4; ++r2) {
      Cb1[p][r2] = b1[16 * p + 4 * q + r2];
      W2v[p][r2] = W2[16 * p + 4 * q + r2];
    }
  }
  const float b2s = b2[0];

  const float* xrow = x + (size_t)row * (T_STEPS * NF);
  float*       orow = out + (size_t)row * T_STEPS;

  // lane-local recurrent state: c for hid = 4q+s (s<4) and 16+4q+(s-4) (s>=4)
  float cst[8] = {0, 0, 0, 0, 0, 0, 0, 0};
  f16x8 Bh = mk8(zz, zz, zz, zz);          // h_{-1} = 0
  f32x4 xv = *(const f32x4*)xrow;          // x_0

  #pragma unroll 1
  for (int t = 0; t < T_STEPS; ++t) {
    const int tn = (t + 1 < T_STEPS) ? t + 1 : t;
    const f32x4 xn = *(const f32x4*)(xrow + tn * NF);   // prefetch x_{t+1}

    // ---- all 8 gate tiles + MLP from h_{t-1}, x_t (independent: deep ILP)
    const f16x8 Bz = mk8(q == 0 ? pk16(xv.x, xv.y) : zz,
                         q == 0 ? pk16(xv.z, xv.w) : zz, zz, zz);
    f32x4 D[8];
    #pragma unroll
    for (int tl = 0; tl < 8; ++tl)
      D[tl] = mfma16(Aih[tl], Bz, mfma16(Ahh[tl], Bh, Cb[tl]));
    const f32x4 M0 = mfma16(Aw1[0], Bh, Cb1[0]);
    const f32x4 M1 = mfma16(Aw1[1], Bh, Cb1[1]);

    // ---- d_{t-1} = sigmoid(relu(M)*W2 + b2)  (r10 reduce order)
    float y = 0.0f;
    #pragma unroll
    for (int r2 = 0; r2 < 4; ++r2) {
      y = fmaf(W2v[0][r2], fmaxf(M0[r2], 0.0f), y);
      y = fmaf(W2v[1][r2], fmaxf(M1[r2], 0.0f), y);
    }
    y += __builtin_bit_cast(float, __builtin_amdgcn_ds_swizzle(
             __builtin_bit_cast(int, y), 0x401F));      // xor-16 (q^1)
    y += __shfl_xor(y, 32);                             // q^2
    float dl = fsigmoid(y + b2s);
    dl = t ? dl : 0.0f;                                 // reference d_{-1} = 0
    if (q == 0 && t) orow[t - 1] = dl;

    // ---- fused activation + c/h update, shared-denominator form.
    // s<4 -> even tiles (hid 4q+s), s>=4 -> odd tiles (hid 16+4q+(s-4)).
    // zi=2^(i'), zf=2^(f'), zg=2^(2g'), zo=2^(o') with pre-acts already
    // ke-scaled (= e^{-pre}); clamps keep products <= 2^120 and reproduce
    // the exact saturation limits.
    float hN[8];
    #pragma unroll
    for (int s = 0; s < 8; ++s) {
      const int odd = s >> 2, r2 = s & 3;
      const float zi = ex2(fminf(fmaf(Wd[0 + odd][r2], dl, D[0 + odd][r2]), 40.0f));
      const float zf = ex2(fminf(fmaf(Wd[2 + odd][r2], dl, D[2 + odd][r2]), 40.0f));
      const float zg = ex2(fminf(fmaf(Wd[4 + odd][r2], dl, D[4 + odd][r2]), 40.0f));
      const float zo = ex2(fminf(fmaf(Wd[6 + odd][r2], dl, D[6 + odd][r2]), 40.0f));
      const float af  = 1.0f + zf;
      const float pig = (1.0f + zi) * (1.0f + zg);
      const float R   = __builtin_amdgcn_rcpf(af * pig);
      const float cN  = fmaf(cst[s], pig, (1.0f - zg) * af) * R;
      cst[s] = cN;
      const float zc = ex2(fminf(-2.0f * LOG2E * cN, 80.0f));
      const float R2 = __builtin_amdgcn_rcpf((1.0f + zo) * (1.0f + zc));
      hN[s] = (1.0f - zc) * R2;
    }
    // Bh slot j (j<4): h[4q+j] = hN[j]; (j>=4): h[16+4q+(j-4)] = hN[j]
    Bh = mk8(pk16(hN[0], hN[1]), pk16(hN[2], hN[3]),
             pk16(hN[4], hN[5]), pk16(hN[6], hN[7]));
    xv = xn;
  }

  // ---- epilogue: d_{T-1} from h_{T-1} (exact r10)
  const f32x4 M0 = mfma16(Aw1[0], Bh, Cb1[0]);
  const f32x4 M1 = mfma16(Aw1[1], Bh, Cb1[1]);
  float y = 0.0f;
  #pragma unroll
  for (int r2 = 0; r2 < 4; ++r2) {
    y = fmaf(W2v[0][r2], fmaxf(M0[r2], 0.0f), y);
    y = fmaf(W2v[1][r2], fmaxf(M1[r2], 0.0f), y);
  }
  y += __builtin_bit_cast(float, __builtin_amdgcn_ds_swizzle(
           __builtin_bit_cast(int, y), 0x401F));
  y += __shfl_xor(y, 32);
  const float dl = fsigmoid(y + b2s);
  if (q == 0) orow[T_STEPS - 1] = dl;
}

extern "C" void kernel_launch(void* const* d_in, const int* in_sizes, int n_in,
                              void* d_out, int out_size, void* d_ws, size_t ws_size,
                              hipStream_t stream) {
  const float* x    = (const float*)d_in[0];
  const float* bn_g = (const float*)d_in[1];
  const float* bn_b = (const float*)d_in[2];
  const float* bn_m = (const float*)d_in[3];
  const float* bn_v = (const float*)d_in[4];
  const float* W_ih = (const float*)d_in[5];
  const float* b_ih = (const float*)d_in[6];
  const float* W_hh = (const float*)d_in[7];
  const float* b_hh = (const float*)d_in[8];
  const float* W1   = (const float*)d_in[9];
  const float* b1   = (const float*)d_in[10];
  const float* W2   = (const float*)d_in[11];
  const float* b2   = (const float*)d_in[12];
  float* out = (float*)d_out;

  const int B = in_sizes[0] / (T_STEPS * NF);   // 8192
  const int grid = B / 16;                      // one 64-thread wave per 16 rows

  hipLaunchKernelGGL(hedge_kernel, dim3(grid), dim3(64), 0, stream,
                     x, bn_g, bn_b, bn_m, bn_v, W_ih, b_ih, W_hh, b_hh,
                     W1, b1, W2, b2, out);
}

// Round 9
// 497.439 us; speedup vs baseline: 8.3368x; 1.0576x over previous
//
#include <hip/hip_runtime.h>
#include <math.h>

#define T_STEPS 512
#define NF 4
#define HID 32
#define BN_EPS 1e-5f
#define LOG2E 1.44269504088896340736f

typedef float    f32x4 __attribute__((ext_vector_type(4)));
typedef _Float16 f16x2 __attribute__((ext_vector_type(2)));
typedef _Float16 f16x8 __attribute__((ext_vector_type(8)));

struct F8 { f16x2 p[4]; };

__device__ __forceinline__ f16x2 pk16(float x, float y) {
  return __builtin_bit_cast(f16x2, __builtin_amdgcn_cvt_pkrtz(x, y));
}
// round-to-nearest pack (2x v_cvt_f16_f32 + pack) — used for the new
// W2/relu(M) fragments only; halves RTZ bias on the output-feeding path.
__device__ __forceinline__ f16x2 pk16n(float x, float y) {
  f16x2 r; r.x = (_Float16)x; r.y = (_Float16)y; return r;
}
__device__ __forceinline__ f16x8 mk8(f16x2 a, f16x2 b, f16x2 c, f16x2 d) {
  F8 f; f.p[0] = a; f.p[1] = b; f.p[2] = c; f.p[3] = d;
  return __builtin_bit_cast(f16x8, f);
}
#if __has_builtin(__builtin_amdgcn_exp2f)
__device__ __forceinline__ float ex2(float x) { return __builtin_amdgcn_exp2f(x); }
#else
__device__ __forceinline__ float ex2(float x) { return exp2f(x); }
#endif
__device__ __forceinline__ float fsigmoid(float x) {
  return __builtin_amdgcn_rcpf(1.0f + __expf(-x));   // validated r1..r16
}
__device__ __forceinline__ f32x4 mfma16(f16x8 a, f16x8 b, f32x4 c) {
  return __builtin_amdgcn_mfma_f32_16x16x32_f16(a, b, c, 0, 0, 0);
}

// r17 = r16 with ONE change: the dl cross-lane reduce (8-deep serial fmaf +
// ds_swizzle + shfl_xor + adds, ~250 cyc of un-hideable dependency latency
// per step -- the largest stall component at 1 wave/SIMD) is replaced by a
// second-layer MFMA:
//   y[n] = sum_k W2[k]*relu(M)[k][n] is a matvec. Lane (n,q) holds
//   M[4q+r][n], M[16+4q+r][n] = exactly the B-fragment k-slots pi(8q+j)
//   (same mapping as the Bh pack). Pack PB = relu(M) as a B-fragment,
//   build constant A-fragment Aw2 with A[m][k] = W2[k] for all m (slot j =
//   W2[pi(8q+j)], uses lane's own q), then one mfma16(Aw2, PB, b2) puts
//   y[n]+b2 in EVERY reg of EVERY lane. Zero cross-lane ops remain.
// Safety: r11 vs r12 vs r13 byte-identical outputs proved dl code-motion is
// pure code motion; this changes only the reduce arithmetic (f32 serial ->
// f16-in/f32-acc MFMA, RTN packs). Error budget ~5e-4 on top of 1.95e-3,
// threshold 9.8e-3.
// Everything else verbatim r16 (r10 structure: 1 wave/job, no LDS/barriers;
// shared-denominator activations, 7 trans/hid).
__global__ __launch_bounds__(64, 1) void hedge_kernel(
    const float* __restrict__ x,
    const float* __restrict__ bn_g, const float* __restrict__ bn_b,
    const float* __restrict__ bn_m, const float* __restrict__ bn_v,
    const float* __restrict__ W_ih, const float* __restrict__ b_ih,
    const float* __restrict__ W_hh, const float* __restrict__ b_hh,
    const float* __restrict__ W1,   const float* __restrict__ b1,
    const float* __restrict__ W2,   const float* __restrict__ b2,
    float* __restrict__ out)
{
  const int lane = threadIdx.x & 63;
  const int n    = lane & 15;          // batch column (and A-fragment row m)
  const int q    = lane >> 4;          // quad
  const int row  = blockIdx.x * 16 + n;

  // ---- fold BatchNorm (z*scale + shift) into weights and bias
  float scale[5], shift[5];
  #pragma unroll
  for (int f = 0; f < 5; ++f) {
    float s = bn_g[f] * rsqrtf(bn_v[f] + BN_EPS);
    scale[f] = s;
    shift[f] = fmaf(-bn_m[f], s, bn_b[f]);
  }

  const f16x2 zz = {(_Float16)0, (_Float16)0};

  // A/B layouts + K-permutation identical to r8..r16 (verified):
  //   A: m=lane&15, k-slot j -> pi(8q+j) = (j<4) ? 4q+j : 16+4q+(j-4)
  //   D: n=lane&15, m=4q+reg
  // Tile t covers gate-rows [16t, 16t+16): i=tiles 0,1  f=2,3  g=4,5  o=6,7.
  f16x8 Ahh[8], Aih[8];
  f32x4 Cb[8], Wd[8];
  #pragma unroll
  for (int tl = 0; tl < 8; ++tl) {
    const float ke = (tl == 4 || tl == 5) ? -2.0f * LOG2E : -LOG2E;
    const float* Wr = &W_hh[(16 * tl + n) * HID];
    const f32x4 lo = *(const f32x4*)&Wr[4 * q];
    const f32x4 hi = *(const f32x4*)&Wr[16 + 4 * q];
    Ahh[tl] = mk8(pk16(ke * lo.x, ke * lo.y), pk16(ke * lo.z, ke * lo.w),
                  pk16(ke * hi.x, ke * hi.y), pk16(ke * hi.z, ke * hi.w));
    const float* Wi = &W_ih[(16 * tl + n) * 5];
    Aih[tl] = mk8(q == 0 ? pk16(ke * Wi[0] * scale[0], ke * Wi[1] * scale[1]) : zz,
                  q == 0 ? pk16(ke * Wi[2] * scale[2], ke * Wi[3] * scale[3]) : zz,
                  zz, zz);
    #pragma unroll
    for (int r2 = 0; r2 < 4; ++r2) {
      const int rr = 16 * tl + 4 * q + r2;
      float a = b_ih[rr] + b_hh[rr];
      #pragma unroll
      for (int f = 0; f < 5; ++f) a = fmaf(W_ih[rr * 5 + f], shift[f], a);
      Cb[tl][r2] = ke * a;
      Wd[tl][r2] = ke * W_ih[rr * 5 + 4] * scale[4];
    }
  }
  // MLP layer-1 fragments (unscaled)
  f16x8 Aw1[2];
  f32x4 Cb1[2];
  f32x4 W2v[2];
  #pragma unroll
  for (int p = 0; p < 2; ++p) {
    const float* Wr = &W1[(16 * p + n) * HID];
    const f32x4 lo = *(const f32x4*)&Wr[4 * q];
    const f32x4 hi = *(const f32x4*)&Wr[16 + 4 * q];
    Aw1[p] = mk8(pk16(lo.x, lo.y), pk16(lo.z, lo.w),
                 pk16(hi.x, hi.y), pk16(hi.z, hi.w));
    #pragma unroll
    for (int r2 = 0; r2 < 4; ++r2) {
      Cb1[p][r2] = b1[16 * p + 4 * q + r2];
      W2v[p][r2] = W2[16 * p + 4 * q + r2];
    }
  }
  // MLP layer-2 as constant A-fragment: A[m][k] = W2[k] for all m.
  // Slot j = W2[pi(8q+j)]: j<4 -> W2[4q+j] = W2v[0][j]; j>=4 -> W2v[1][j-4].
  const f16x8 Aw2 = mk8(pk16n(W2v[0][0], W2v[0][1]), pk16n(W2v[0][2], W2v[0][3]),
                        pk16n(W2v[1][0], W2v[1][1]), pk16n(W2v[1][2], W2v[1][3]));
  const float b2s = b2[0];
  const f32x4 Cb2 = {b2s, b2s, b2s, b2s};

  const float* xrow = x + (size_t)row * (T_STEPS * NF);
  float*       orow = out + (size_t)row * T_STEPS;

  // lane-local recurrent state: c for hid = 4q+s (s<4) and 16+4q+(s-4) (s>=4)
  float cst[8] = {0, 0, 0, 0, 0, 0, 0, 0};
  f16x8 Bh = mk8(zz, zz, zz, zz);          // h_{-1} = 0
  f32x4 xv = *(const f32x4*)xrow;          // x_0

  #pragma unroll 1
  for (int t = 0; t < T_STEPS; ++t) {
    const int tn = (t + 1 < T_STEPS) ? t + 1 : t;
    const f32x4 xn = *(const f32x4*)(xrow + tn * NF);   // prefetch x_{t+1}

    // ---- all 8 gate tiles + MLP layer-1 from h_{t-1}, x_t
    const f16x8 Bz = mk8(q == 0 ? pk16(xv.x, xv.y) : zz,
                         q == 0 ? pk16(xv.z, xv.w) : zz, zz, zz);
    f32x4 D[8];
    #pragma unroll
    for (int tl = 0; tl < 8; ++tl)
      D[tl] = mfma16(Aih[tl], Bz, mfma16(Ahh[tl], Bh, Cb[tl]));
    const f32x4 M0 = mfma16(Aw1[0], Bh, Cb1[0]);
    const f32x4 M1 = mfma16(Aw1[1], Bh, Cb1[1]);

    // ---- d_{t-1}: layer-2 via MFMA; PB = relu(M) packed as B-fragment
    //      (slot j<4 = relu(M0[j]) = relu(M)[4q+j][n]; j>=4 = relu(M1[j-4]))
    const f16x8 PB = mk8(
        pk16n(fmaxf(M0[0], 0.0f), fmaxf(M0[1], 0.0f)),
        pk16n(fmaxf(M0[2], 0.0f), fmaxf(M0[3], 0.0f)),
        pk16n(fmaxf(M1[0], 0.0f), fmaxf(M1[1], 0.0f)),
        pk16n(fmaxf(M1[2], 0.0f), fmaxf(M1[3], 0.0f)));
    const f32x4 Y = mfma16(Aw2, PB, Cb2);   // every reg = y[n] + b2
    float dl = fsigmoid(Y[0]);
    dl = t ? dl : 0.0f;                     // reference d_{-1} = 0
    if (q == 0 && t) orow[t - 1] = dl;

    // ---- fused activation + c/h update, shared-denominator form (r16).
    // s<4 -> even tiles (hid 4q+s), s>=4 -> odd tiles (hid 16+4q+(s-4)).
    float hN[8];
    #pragma unroll
    for (int s = 0; s < 8; ++s) {
      const int odd = s >> 2, r2 = s & 3;
      const float zi = ex2(fminf(fmaf(Wd[0 + odd][r2], dl, D[0 + odd][r2]), 40.0f));
      const float zf = ex2(fminf(fmaf(Wd[2 + odd][r2], dl, D[2 + odd][r2]), 40.0f));
      const float zg = ex2(fminf(fmaf(Wd[4 + odd][r2], dl, D[4 + odd][r2]), 40.0f));
      const float zo = ex2(fminf(fmaf(Wd[6 + odd][r2], dl, D[6 + odd][r2]), 40.0f));
      const float af  = 1.0f + zf;
      const float pig = (1.0f + zi) * (1.0f + zg);
      const float R   = __builtin_amdgcn_rcpf(af * pig);
      const float cN  = fmaf(cst[s], pig, (1.0f - zg) * af) * R;
      cst[s] = cN;
      const float zc = ex2(fminf(-2.0f * LOG2E * cN, 80.0f));
      const float R2 = __builtin_amdgcn_rcpf((1.0f + zo) * (1.0f + zc));
      hN[s] = (1.0f - zc) * R2;
    }
    // Bh slot j (j<4): h[4q+j] = hN[j]; (j>=4): h[16+4q+(j-4)] = hN[j]
    Bh = mk8(pk16(hN[0], hN[1]), pk16(hN[2], hN[3]),
             pk16(hN[4], hN[5]), pk16(hN[6], hN[7]));
    xv = xn;
  }

  // ---- epilogue: d_{T-1} from h_{T-1} (same MFMA layer-2)
  const f32x4 M0 = mfma16(Aw1[0], Bh, Cb1[0]);
  const f32x4 M1 = mfma16(Aw1[1], Bh, Cb1[1]);
  const f16x8 PB = mk8(
      pk16n(fmaxf(M0[0], 0.0f), fmaxf(M0[1], 0.0f)),
      pk16n(fmaxf(M0[2], 0.0f), fmaxf(M0[3], 0.0f)),
      pk16n(fmaxf(M1[0], 0.0f), fmaxf(M1[1], 0.0f)),
      pk16n(fmaxf(M1[2], 0.0f), fmaxf(M1[3], 0.0f)));
  const f32x4 Y = mfma16(Aw2, PB, Cb2);
  const float dl = fsigmoid(Y[0]);
  if (q == 0) orow[T_STEPS - 1] = dl;
}

extern "C" void kernel_launch(void* const* d_in, const int* in_sizes, int n_in,
                              void* d_out, int out_size, void* d_ws, size_t ws_size,
                              hipStream_t stream) {
  const float* x    = (const float*)d_in[0];
  const float* bn_g = (const float*)d_in[1];
  const float* bn_b = (const float*)d_in[2];
  const float* bn_m = (const float*)d_in[3];
  const float* bn_v = (const float*)d_in[4];
  const float* W_ih = (const float*)d_in[5];
  const float* b_ih = (const float*)d_in[6];
  const float* W_hh = (const float*)d_in[7];
  const float* b_hh = (const float*)d_in[8];
  const float* W1   = (const float*)d_in[9];
  const float* b1   = (const float*)d_in[10];
  const float* W2   = (const float*)d_in[11];
  const float* b2   = (const float*)d_in[12];
  float* out = (float*)d_out;

  const int B = in_sizes[0] / (T_STEPS * NF);   // 8192
  const int grid = B / 16;                      // one 64-thread wave per 16 rows

  hipLaunchKernelGGL(hedge_kernel, dim3(grid), dim3(64), 0, stream,
                     x, bn_g, bn_b, bn_m, bn_v, W_ih, b_ih, W_hh, b_hh,
                     W1, b1, W2, b2, out);
}